// Round 11
// baseline (352.472 us; speedup 1.0000x reference)
//
#include <hip/hip_runtime.h>
#include <hip/hip_bf16.h>

typedef unsigned short ushort_t;
typedef unsigned int uint_t;

typedef __bf16 bf16x8 __attribute__((ext_vector_type(8)));
typedef float f32x4 __attribute__((ext_vector_type(4)));
typedef float f32x2 __attribute__((ext_vector_type(2)));
typedef ushort_t us8 __attribute__((ext_vector_type(8)));

__device__ __forceinline__ float bf2f(ushort_t u) {
    return __uint_as_float(((uint_t)u) << 16);
}
__device__ __forceinline__ ushort_t f2bf(float f) {
    uint_t x = __float_as_uint(f);
    uint_t r = (x + 0x7FFFu + ((x >> 16) & 1u)) >> 16;
    return (ushort_t)r;
}
// v_rcp_f32 (~1ulp) instead of the IEEE div sequence (~10 instr incl.
// quarter-rate TRANS). exp->inf gives rcp(inf)=0: correct saturation.
__device__ __forceinline__ float fast_rcp(float x) {
    float r;
    asm("v_rcp_f32 %0, %1" : "=v"(r) : "v"(x));
    return r;
}
__device__ __forceinline__ float sigmoidf_fast(float x) {
    return fast_rcp(1.0f + __expf(-x));
}

// Geometry constants
#define PP 12544          // pixels per image plane = 112*112 (= 49*256)
#define PLANE 25690112ULL // elements per k-plane of U2t = 8*256*12544

// ---------------------------------------------------------------------------
// Kernel 1: permute+transpose W2 (fp32 256x768) -> W2t (bf16 768x256).
// (verbatim verified)
// ---------------------------------------------------------------------------
__global__ __launch_bounds__(256) void permute_w2(const float* __restrict__ W2,
                                                  ushort_t* __restrict__ W2t) {
    int i = blockIdx.x * 256 + threadIdx.x;   // 768*256 total
    int np = i >> 8;        // n' in [0,768)
    int k  = i & 255;       // k  in [0,256)
    int kk  = np >> 8;      // 0..2
    int rem = np & 255;
    int dir = rem >> 7;
    int d   = rem & 127;
    int oc = dir * 384 + d * 3 + kk;
    W2t[np * 256 + k] = f2bf(W2[k * 768 + oc]);
}

// ---------------------------------------------------------------------------
// Kernel 2: fused patch-extract + GEMM1 (K=12, register weights) + SRU scan
// over Wp. Block = (hp,b), thread = channel (dir,d). Writes only
// H1a[b][p][ch] (bf16, tid-coalesced). rcp-sigmoid + register-pipelined
// patch row + pk-fma GEMM1. (verbatim from r10 PASSED, 339us total)
// ---------------------------------------------------------------------------
__global__ __launch_bounds__(256) void scan1(const float* __restrict__ x,
                                             const float* __restrict__ W1,
                                             const float* __restrict__ wc1,
                                             const float* __restrict__ b1,
                                             ushort_t* __restrict__ H1a) {
    __shared__ float patch[112 * 12];       // 5376 B only
    const int n1 = blockIdx.x;
    const int hp = n1 >> 3, b = n1 & 7;
    const int tid = threadIdx.x;

    for (int e = tid; e < 1344; e += 256) {
        int c = e / 448;
        int rem = e % 448;
        int wh = rem / 224;
        int pos = rem % 224;            // 2*wp + ww
        float v = x[((b * 3 + c) * 224 + (2 * hp + wh)) * 224 + pos];
        patch[(pos >> 1) * 12 + c * 4 + wh * 2 + (pos & 1)] = v;
    }

    f32x2 w01[12], w23[12];
    const float4* W1v = (const float4*)W1;
#pragma unroll
    for (int j = 0; j < 12; ++j) {
        float4 wv = W1v[j * 256 + tid];
        w01[j][0] = wv.x; w01[j][1] = wv.y;
        w23[j][0] = wv.z; w23[j][1] = wv.w;
    }

    const float vf = wc1[tid],       vr = wc1[256 + tid];
    const float bfv = b1[tid],       brv = b1[256 + tid];
    const int dir = tid >> 7;        // wave-uniform (waves 0-1 fwd, 2-3 bwd)

    __syncthreads();

    // Store offset walks H1a incrementally (row stride 256 ch).
    const size_t h1base = ((size_t)b * PP + (size_t)hp * 112) * 256 + tid;
    size_t hOff = h1base + (dir ? (size_t)111 * 256 : 0);
    const long hstep = dir ? -256 : 256;

    // Register-pipelined patch row: q* holds row tt(t); load tt(t+1) early.
    const float* prow = patch + (dir ? 111 * 12 : 0);
    const int rstep = dir ? -12 : 12;
    float4 q0 = ((const float4*)prow)[0];
    float4 q1 = ((const float4*)prow)[1];
    float4 q2 = ((const float4*)prow)[2];

    float cst = 0.0f;
    for (int t = 0; t < 112; ++t) {
        const float* pn = prow + ((t < 111) ? rstep : 0);
        float4 n0 = ((const float4*)pn)[0];
        float4 n1v = ((const float4*)pn)[1];
        float4 n2 = ((const float4*)pn)[2];

        float pj[12] = {q0.x, q0.y, q0.z, q0.w, q1.x, q1.y, q1.z, q1.w,
                        q2.x, q2.y, q2.z, q2.w};
        f32x2 u01 = {0.f, 0.f}, u23 = {0.f, 0.f};
#pragma unroll
        for (int j = 0; j < 12; ++j) {
            f32x2 pv2 = {pj[j], pj[j]};
            u01 = w01[j] * pv2 + u01;   // contracts to v_pk_fma_f32
            u23 = w23[j] * pv2 + u23;
        }
        float u0 = u01[0], u1 = u01[1], u2 = u23[0], u3 = u23[1];
        float f = sigmoidf_fast(u1 + vf * cst + bfv);
        cst = f * cst + (1.0f - f) * u0;
        float r = sigmoidf_fast(u2 + vr * cst + brv);
        float h = r * cst + (1.0f - r) * u3;
        H1a[hOff] = f2bf(h);

        hOff += hstep;
        prow = pn;
        q0 = n0; q1 = n1v; q2 = n2;
    }
}

// ---------------------------------------------------------------------------
// Kernel 3: bf16 MFMA GEMM: H1a(M x 256) @ W2t^T, M=100352 (m = b*PP+p).
// v6: 256x128 tile, 512 threads / 8 waves. Per-wave schedule IDENTICAL to
// the verified r4 kernel (2-barrier K-loop, K-unroll x2); only the tile is
// taller: wm spans 0..3 (4 p-subtiles of 64). LDS 48KB -> 3 blocks/CU =
// 24 waves/CU (vs ~9 at 128^2): raises cross-block stage/compute overlap
// without touching the schedule (the lever both failed pipelines missed).
// A/B probe: if gemm2 stays ~96us, it is write-bound at ~2.2TB/s (211MB)
// and is at its floor. T1 swizzle: 2352 = 8 XCDs x 294, y-major, bijective.
// Staging per kb: A 4 instr/thread (8w x 2q x 16 rows = 256), B 2
// (8w x 16 = 128). Plane-3 write-out: 512 thr cover 256p x 64ch exactly.
// ---------------------------------------------------------------------------
__global__ __launch_bounds__(512) void gemm2(const ushort_t* __restrict__ A,
                                             const ushort_t* __restrict__ Bt,
                                             ushort_t* __restrict__ U2t) {
    __shared__ ushort_t As[2][256 * 32];   // [half][row][k] 64B rows, 16 KB each
    __shared__ ushort_t Bs[2][128 * 32];   // 8 KB each; total 48 KB

    // T1 swizzle: blockIdx.x -> (nx, ny), y-major within each XCD's chunk.
    const int l    = blockIdx.x;           // 0..2351
    const int pair = (l & 7) * 294 + (l >> 3);
    const int nx   = pair % 6;             // n-tile 0..5
    const int ny   = pair / 6;             // m-panel 0..391 (256 rows each)

    const int m0 = ny * 256;
    const int bb = ny / 49;                // batch index (m0 == bb*PP + p0)
    const int p0 = (ny % 49) * 256;
    const int n0 = nx * 128;
    const int kidx = n0 >> 8;              // 0..2
    const int ch0  = n0 & 255;             // 0 or 128
    const int tid = threadIdx.x;
    const int w = tid >> 6, lane = tid & 63;   // w 0..7
    const int wm = w >> 1, wn = w & 1;         // wm 0..3 (p), wn 0..1 (ch)
    const int lr = lane >> 2;
    const int lc = (lane & 3) * 8;
    const int ln16 = lane & 15;
    const int k8 = (lane >> 4) * 8;

    f32x4 acc[4][4] = {};

    for (int kb = 0; kb < 256; kb += 64) {
        if (kb) __syncthreads();
#pragma unroll
        for (int h = 0; h < 2; ++h) {
            // A: 256 rows via 8 waves x 2 chunks x 16 rows.
#pragma unroll
            for (int q = 0; q < 2; ++q) {
                int r = w * 32 + q * 16;   // wave-uniform base row
                const ushort_t* gA = A + (size_t)(m0 + r + lr) * 256 + kb + h * 32 + lc;
                __builtin_amdgcn_global_load_lds(
                    (const __attribute__((address_space(1))) uint_t*)gA,
                    (__attribute__((address_space(3))) uint_t*)(As[h] + r * 32), 16, 0, 0);
            }
            // B: 128 rows via 8 waves x 16 rows.
            {
                int r = w * 16;
                const ushort_t* gB = Bt + (size_t)(n0 + r + lr) * 256 + kb + h * 32 + lc;
                __builtin_amdgcn_global_load_lds(
                    (const __attribute__((address_space(1))) uint_t*)gB,
                    (__attribute__((address_space(3))) uint_t*)(Bs[h] + r * 32), 16, 0, 0);
            }
        }
        __syncthreads();

#pragma unroll
        for (int h = 0; h < 2; ++h) {
            bf16x8 af[4], bf[4];
#pragma unroll
            for (int i = 0; i < 4; ++i) {
                af[i] = *(const bf16x8*)(As[h] + (wm * 64 + i * 16 + ln16) * 32 + k8);
                bf[i] = *(const bf16x8*)(Bs[h] + (wn * 64 + i * 16 + ln16) * 32 + k8);
            }
#pragma unroll
            for (int i = 0; i < 4; ++i)
#pragma unroll
                for (int j = 0; j < 4; ++j)
                    acc[i][j] = __builtin_amdgcn_mfma_f32_16x16x32_bf16(
                        af[i], bf[j], acc[i][j], 0, 0, 0);
        }

        // Plane-3 transpose write-out from the staged As tile (raw bits).
        // 512 threads: cl = ch within kb chunk (64), pc = p chunk (8 x 32).
        if (nx < 4 && kb == nx * 64) {
            const int cl = tid & 63;
            const int pc = tid >> 6;          // 0..7 (wave-uniform)
            const int hh = cl >> 5;           // As half
            const int cc = cl & 31;           // k within half
            const size_t p3 = 3 * PLANE
                            + (size_t)(bb * 256 + kb + cl) * PP + p0 + pc * 32;
#pragma unroll
            for (int j8 = 0; j8 < 4; ++j8) {
                us8 v;
#pragma unroll
                for (int j = 0; j < 8; ++j)
                    v[j] = As[hh][(pc * 32 + j8 * 8 + j) * 32 + cc];
                *(us8*)(U2t + p3 + j8 * 8) = v;
            }
        }
    }

    // Epilogue: C/D layout col(N)=lane&15, row(M)=(lane>>4)*4+reg.
    const int rq = (lane >> 4) * 4;
    const size_t planeBase = (size_t)kidx * PLANE + (size_t)(bb * 256 + ch0) * PP;
#pragma unroll
    for (int i = 0; i < 4; ++i) {
        int p = p0 + wm * 64 + i * 16 + rq;
#pragma unroll
        for (int j = 0; j < 4; ++j) {
            int ch_l = wn * 64 + j * 16 + ln16;
            ushort4 v;
            v.x = f2bf(acc[i][j][0]);
            v.y = f2bf(acc[i][j][1]);
            v.z = f2bf(acc[i][j][2]);
            v.w = f2bf(acc[i][j][3]);
            *(ushort4*)(U2t + planeBase + (size_t)ch_l * PP + p) = v;
        }
    }
}

// ---------------------------------------------------------------------------
// Kernel 4: SRU scan over hp, writes d_out directly (b,ch,hp,wp).
// 256 threads = 2 ch x 128 lanes (wp>=112 idle), wave-uniform dir,
// grid (128,8) = 1024 blocks. Depth-14 shift-register prefetch, rcp-sigmoid.
// (verbatim from r10 PASSED)
// ---------------------------------------------------------------------------
__global__ __launch_bounds__(256) void scan2(const ushort_t* __restrict__ U2t,
                                             const float* __restrict__ wc2,
                                             const float* __restrict__ b2,
                                             float* __restrict__ out) {
    const int cb = blockIdx.x;             // 0..127
    const int b  = blockIdx.y;             // 0..7
    const int tid = threadIdx.x;
    const int ch = cb * 2 + (tid >> 7);    // 0..255
    const int wp = tid & 127;
    if (wp >= 112) return;
    const int dir = ch >> 7;
    const float SCALE_X = 1.41421356237309515f;

    const float vf = wc2[ch],  vr = wc2[256 + ch];
    const float bfv = b2[ch],  brv = b2[256 + ch];

    const int tt0 = dir ? 111 : 0;
    const long dstep = dir ? -112 : 112;   // hp stride in U2t planes
    const long ostep = dir ? -112 : 112;   // hp stride in out

    const ushort_t* P = U2t;
    long oOff = (long)((size_t)(b * 256 + ch) * 112 + tt0) * 112 + wp;

    // Depth-14 pipeline: buf[s] holds the 4 plane values for step t with
    // t%14 == s. Preload t=0..12; qp ends at addr(t=13).
    ushort_t buf[14][4];
    long qp = (long)((size_t)(b * 256 + ch) * PP) + tt0 * 112 + wp;
#pragma unroll
    for (int i = 0; i < 13; ++i) {
        buf[i][0] = P[qp];
        buf[i][1] = P[PLANE + qp];
        buf[i][2] = P[2 * PLANE + qp];
        buf[i][3] = P[3 * PLANE + qp];
        qp += dstep;
    }

    float cst = 0.0f;
    for (int tb = 0; tb < 8; ++tb) {
#pragma unroll
        for (int u = 0; u < 14; ++u) {
            const int t = tb * 14 + u;
            // prefetch step t+13 into slot (u+13)%14 (static index); past
            // the end, re-load t=111's row (in-bounds, value unused).
            buf[(u + 13) % 14][0] = P[qp];
            buf[(u + 13) % 14][1] = P[PLANE + qp];
            buf[(u + 13) % 14][2] = P[2 * PLANE + qp];
            buf[(u + 13) % 14][3] = P[3 * PLANE + qp];
            qp += (t < 98) ? dstep : 0;

            float u0 = bf2f(buf[u][0]);
            float u1 = bf2f(buf[u][1]);
            float u2v = bf2f(buf[u][2]);
            float xp = bf2f(buf[u][3]) * SCALE_X;
            float f = sigmoidf_fast(u1 + vf * cst + bfv);
            cst = f * cst + (1.0f - f) * u0;
            float r = sigmoidf_fast(u2v + vr * cst + brv);
            out[oOff] = r * cst + (1.0f - r) * xp;
            oOff += ostep;
        }
    }
}

// ---------------------------------------------------------------------------
// Launch. Workspace layout (bytes):
//   H1a bf16 [b][p][ch] 8*12544*256       @ 0          (51,380,224)
//   U2t bf16 4 planes [k][b][ch][p]       @ 51380224   (205,520,896)
//   W2t bf16 768*256                      @ 256901120  (393,216)
// ---------------------------------------------------------------------------
extern "C" void kernel_launch(void* const* d_in, const int* in_sizes, int n_in,
                              void* d_out, int out_size, void* d_ws, size_t ws_size,
                              hipStream_t stream) {
    const float* x   = (const float*)d_in[0];
    const float* W1  = (const float*)d_in[1];
    const float* wc1 = (const float*)d_in[2];
    const float* b1  = (const float*)d_in[3];
    const float* W2  = (const float*)d_in[4];
    const float* wc2 = (const float*)d_in[5];
    const float* b2  = (const float*)d_in[6];
    float* out = (float*)d_out;

    char* ws = (char*)d_ws;
    ushort_t* H1a = (ushort_t*)(ws);
    ushort_t* U2t = (ushort_t*)(ws + 51380224);
    ushort_t* W2t = (ushort_t*)(ws + 51380224 + 205520896);

    permute_w2<<<768, 256, 0, stream>>>(W2, W2t);
    scan1<<<896, 256, 0, stream>>>(x, W1, wc1, b1, H1a);
    gemm2<<<2352, 512, 0, stream>>>(H1a, W2t, U2t);
    scan2<<<dim3(128, 8), 256, 0, stream>>>(U2t, wc2, b2, out);
}

// Round 12
// 337.637 us; speedup vs baseline: 1.0439x; 1.0439x over previous
//
#include <hip/hip_runtime.h>
#include <hip/hip_bf16.h>

typedef unsigned short ushort_t;
typedef unsigned int uint_t;

typedef __bf16 bf16x8 __attribute__((ext_vector_type(8)));
typedef float f32x4 __attribute__((ext_vector_type(4)));
typedef float f32x2 __attribute__((ext_vector_type(2)));
typedef ushort_t us8 __attribute__((ext_vector_type(8)));

__device__ __forceinline__ float bf2f(ushort_t u) {
    return __uint_as_float(((uint_t)u) << 16);
}
__device__ __forceinline__ ushort_t f2bf(float f) {
    uint_t x = __float_as_uint(f);
    uint_t r = (x + 0x7FFFu + ((x >> 16) & 1u)) >> 16;
    return (ushort_t)r;
}
// v_rcp_f32 (~1ulp) instead of the IEEE div sequence (~10 instr incl.
// quarter-rate TRANS). exp->inf gives rcp(inf)=0: correct saturation.
__device__ __forceinline__ float fast_rcp(float x) {
    float r;
    asm("v_rcp_f32 %0, %1" : "=v"(r) : "v"(x));
    return r;
}
__device__ __forceinline__ float sigmoidf_fast(float x) {
    return fast_rcp(1.0f + __expf(-x));
}

// Geometry constants
#define PP 12544          // pixels per image plane = 112*112 (= 98*128)
#define PLANE 25690112ULL // elements per k-plane of U2t = 8*256*12544

// ---------------------------------------------------------------------------
// Kernel 1: fused patch-extract + GEMM1 (K=12, register weights) + SRU scan
// over Wp. Block = (hp,b), thread = channel (dir,d). Writes only
// H1a[b][p][ch] (bf16, tid-coalesced). rcp-sigmoid + register-pipelined
// patch row + pk-fma GEMM1 (verbatim from r10 PASSED, 339us total).
// v6: absorbs permute_w2 — blocks n1<768 write W2t row n1 (fp32 256x768 ->
// bf16 768x256 permuted) before scan work. W2t consumed only by gemm2, so
// the kernel boundary is the needed fence; one launch removed.
// ---------------------------------------------------------------------------
__global__ __launch_bounds__(256) void scan1(const float* __restrict__ x,
                                             const float* __restrict__ W1,
                                             const float* __restrict__ wc1,
                                             const float* __restrict__ b1,
                                             const float* __restrict__ W2,
                                             ushort_t* __restrict__ W2t,
                                             ushort_t* __restrict__ H1a) {
    __shared__ float patch[112 * 12];       // 5376 B only
    const int n1 = blockIdx.x;
    const int hp = n1 >> 3, b = n1 & 7;
    const int tid = threadIdx.x;

    // Folded permute_w2: row np = n1 of W2t (one element per thread).
    if (n1 < 768) {
        const int kk  = n1 >> 8;      // 0..2
        const int rem = n1 & 255;
        const int dirw = rem >> 7;
        const int d   = rem & 127;
        const int oc = dirw * 384 + d * 3 + kk;
        W2t[n1 * 256 + tid] = f2bf(W2[tid * 768 + oc]);
    }

    for (int e = tid; e < 1344; e += 256) {
        int c = e / 448;
        int rem = e % 448;
        int wh = rem / 224;
        int pos = rem % 224;            // 2*wp + ww
        float v = x[((b * 3 + c) * 224 + (2 * hp + wh)) * 224 + pos];
        patch[(pos >> 1) * 12 + c * 4 + wh * 2 + (pos & 1)] = v;
    }

    f32x2 w01[12], w23[12];
    const float4* W1v = (const float4*)W1;
#pragma unroll
    for (int j = 0; j < 12; ++j) {
        float4 wv = W1v[j * 256 + tid];
        w01[j][0] = wv.x; w01[j][1] = wv.y;
        w23[j][0] = wv.z; w23[j][1] = wv.w;
    }

    const float vf = wc1[tid],       vr = wc1[256 + tid];
    const float bfv = b1[tid],       brv = b1[256 + tid];
    const int dir = tid >> 7;        // wave-uniform (waves 0-1 fwd, 2-3 bwd)

    __syncthreads();

    // Store offset walks H1a incrementally (row stride 256 ch).
    const size_t h1base = ((size_t)b * PP + (size_t)hp * 112) * 256 + tid;
    size_t hOff = h1base + (dir ? (size_t)111 * 256 : 0);
    const long hstep = dir ? -256 : 256;

    // Register-pipelined patch row: q* holds row tt(t); load tt(t+1) early.
    const float* prow = patch + (dir ? 111 * 12 : 0);
    const int rstep = dir ? -12 : 12;
    float4 q0 = ((const float4*)prow)[0];
    float4 q1 = ((const float4*)prow)[1];
    float4 q2 = ((const float4*)prow)[2];

    float cst = 0.0f;
    for (int t = 0; t < 112; ++t) {
        const float* pn = prow + ((t < 111) ? rstep : 0);
        float4 n0 = ((const float4*)pn)[0];
        float4 n1v = ((const float4*)pn)[1];
        float4 n2 = ((const float4*)pn)[2];

        float pj[12] = {q0.x, q0.y, q0.z, q0.w, q1.x, q1.y, q1.z, q1.w,
                        q2.x, q2.y, q2.z, q2.w};
        f32x2 u01 = {0.f, 0.f}, u23 = {0.f, 0.f};
#pragma unroll
        for (int j = 0; j < 12; ++j) {
            f32x2 pv2 = {pj[j], pj[j]};
            u01 = w01[j] * pv2 + u01;   // contracts to v_pk_fma_f32
            u23 = w23[j] * pv2 + u23;
        }
        float u0 = u01[0], u1 = u01[1], u2 = u23[0], u3 = u23[1];
        float f = sigmoidf_fast(u1 + vf * cst + bfv);
        cst = f * cst + (1.0f - f) * u0;
        float r = sigmoidf_fast(u2 + vr * cst + brv);
        float h = r * cst + (1.0f - r) * u3;
        H1a[hOff] = f2bf(h);

        hOff += hstep;
        prow = pn;
        q0 = n0; q1 = n1v; q2 = n2;
    }
}

// ---------------------------------------------------------------------------
// Kernel 2: bf16 MFMA GEMM: H1a(M x 256) @ W2t^T, M=100352 (m = b*PP+p).
// 128x128 tile, K-unroll x2 (two BK=32 sub-tiles per barrier pair).
// XCD-aware 1-D grid swizzle (T1): 4704 blocks = 8 XCDs x 588 pairs,
// y-major within each XCD chunk so the 6 n-tiles of an m-panel share one
// XCD's L2 (A-panel fetched once).
// VERBATIM r4 kernel, 5x harness-verified at ~96.5us. Rejected variants:
// drain-0 2-phase (122us), counted-vmcnt 3-buf (117us), 256x128 tile
// (114us) — this structure is the proven local optimum; A/B evidence says
// latency-structure-bound, not BW-bound (r2 moved 364MB at 3.35TB/s).
// ---------------------------------------------------------------------------
__global__ __launch_bounds__(256) void gemm2(const ushort_t* __restrict__ A,
                                             const ushort_t* __restrict__ Bt,
                                             ushort_t* __restrict__ U2t) {
    __shared__ ushort_t As[2][128 * 32];   // [half][row][k] 64B rows, 8 KB each
    __shared__ ushort_t Bs[2][128 * 32];   // total 32 KB

    // T1 swizzle: blockIdx.x -> (nx, ny), y-major within each XCD's chunk.
    const int l    = blockIdx.x;           // 0..4703
    const int pair = (l & 7) * 588 + (l >> 3);
    const int nx   = pair % 6;             // n-tile 0..5
    const int ny   = pair / 6;             // m-panel 0..783

    const int m0 = ny * 128;
    const int bb = ny / 98;                // batch index (m0 == bb*PP + p0)
    const int p0 = (ny % 98) * 128;
    const int n0 = nx * 128;
    const int kidx = n0 >> 8;              // 0..2
    const int ch0  = n0 & 255;             // 0 or 128
    const int tid = threadIdx.x;
    const int w = tid >> 6, lane = tid & 63;
    const int wm = w >> 1, wn = w & 1;
    const int lr = lane >> 2;
    const int lc = (lane & 3) * 8;
    const int ln16 = lane & 15;
    const int k8 = (lane >> 4) * 8;

    f32x4 acc[4][4] = {};

    for (int kb = 0; kb < 256; kb += 64) {
        if (kb) __syncthreads();
#pragma unroll
        for (int h = 0; h < 2; ++h) {
#pragma unroll
            for (int q = 0; q < 2; ++q) {
                int r = w * 32 + q * 16;   // wave-uniform base row of 1KB chunk
                const ushort_t* gA = A + (size_t)(m0 + r + lr) * 256 + kb + h * 32 + lc;
                __builtin_amdgcn_global_load_lds(
                    (const __attribute__((address_space(1))) uint_t*)gA,
                    (__attribute__((address_space(3))) uint_t*)(As[h] + r * 32), 16, 0, 0);
                const ushort_t* gB = Bt + (size_t)(n0 + r + lr) * 256 + kb + h * 32 + lc;
                __builtin_amdgcn_global_load_lds(
                    (const __attribute__((address_space(1))) uint_t*)gB,
                    (__attribute__((address_space(3))) uint_t*)(Bs[h] + r * 32), 16, 0, 0);
            }
        }
        __syncthreads();

#pragma unroll
        for (int h = 0; h < 2; ++h) {
            bf16x8 af[4], bf[4];
#pragma unroll
            for (int i = 0; i < 4; ++i) {
                af[i] = *(const bf16x8*)(As[h] + (wm * 64 + i * 16 + ln16) * 32 + k8);
                bf[i] = *(const bf16x8*)(Bs[h] + (wn * 64 + i * 16 + ln16) * 32 + k8);
            }
#pragma unroll
            for (int i = 0; i < 4; ++i)
#pragma unroll
                for (int j = 0; j < 4; ++j)
                    acc[i][j] = __builtin_amdgcn_mfma_f32_16x16x32_bf16(
                        af[i], bf[j], acc[i][j], 0, 0, 0);
        }

        // Plane-3 transpose write-out from the staged As tile (raw bits).
        if (nx < 4 && kb == nx * 64) {
            const int cl = tid & 63;          // ch-local 0..63 within kb chunk
            const int pc = tid >> 6;          // wave-uniform p chunk (0..3)
            const int hh = cl >> 5;           // As half
            const int cc = cl & 31;           // k within half
            const size_t p3 = 3 * PLANE
                            + (size_t)(bb * 256 + kb + cl) * PP + p0 + pc * 32;
#pragma unroll
            for (int j8 = 0; j8 < 4; ++j8) {
                us8 v;
#pragma unroll
                for (int j = 0; j < 8; ++j)
                    v[j] = As[hh][(pc * 32 + j8 * 8 + j) * 32 + cc];
                *(us8*)(U2t + p3 + j8 * 8) = v;
            }
        }
    }

    // Epilogue: C/D layout col(N)=lane&15, row(M)=(lane>>4)*4+reg.
    const int rq = (lane >> 4) * 4;
    const size_t planeBase = (size_t)kidx * PLANE + (size_t)(bb * 256 + ch0) * PP;
#pragma unroll
    for (int i = 0; i < 4; ++i) {
        int p = p0 + wm * 64 + i * 16 + rq;
#pragma unroll
        for (int j = 0; j < 4; ++j) {
            int ch_l = wn * 64 + j * 16 + ln16;
            ushort4 v;
            v.x = f2bf(acc[i][j][0]);
            v.y = f2bf(acc[i][j][1]);
            v.z = f2bf(acc[i][j][2]);
            v.w = f2bf(acc[i][j][3]);
            *(ushort4*)(U2t + planeBase + (size_t)ch_l * PP + p) = v;
        }
    }
}

// ---------------------------------------------------------------------------
// Kernel 3: SRU scan over hp, writes d_out directly (b,ch,hp,wp).
// 256 threads = 2 ch x 128 lanes (wp>=112 idle), wave-uniform dir,
// grid (128,8) = 1024 blocks. Depth-14 shift-register prefetch, rcp-sigmoid.
// (verbatim from r10 PASSED)
// ---------------------------------------------------------------------------
__global__ __launch_bounds__(256) void scan2(const ushort_t* __restrict__ U2t,
                                             const float* __restrict__ wc2,
                                             const float* __restrict__ b2,
                                             float* __restrict__ out) {
    const int cb = blockIdx.x;             // 0..127
    const int b  = blockIdx.y;             // 0..7
    const int tid = threadIdx.x;
    const int ch = cb * 2 + (tid >> 7);    // 0..255
    const int wp = tid & 127;
    if (wp >= 112) return;
    const int dir = ch >> 7;
    const float SCALE_X = 1.41421356237309515f;

    const float vf = wc2[ch],  vr = wc2[256 + ch];
    const float bfv = b2[ch],  brv = b2[256 + ch];

    const int tt0 = dir ? 111 : 0;
    const long dstep = dir ? -112 : 112;   // hp stride in U2t planes
    const long ostep = dir ? -112 : 112;   // hp stride in out

    const ushort_t* P = U2t;
    long oOff = (long)((size_t)(b * 256 + ch) * 112 + tt0) * 112 + wp;

    // Depth-14 pipeline: buf[s] holds the 4 plane values for step t with
    // t%14 == s. Preload t=0..12; qp ends at addr(t=13).
    ushort_t buf[14][4];
    long qp = (long)((size_t)(b * 256 + ch) * PP) + tt0 * 112 + wp;
#pragma unroll
    for (int i = 0; i < 13; ++i) {
        buf[i][0] = P[qp];
        buf[i][1] = P[PLANE + qp];
        buf[i][2] = P[2 * PLANE + qp];
        buf[i][3] = P[3 * PLANE + qp];
        qp += dstep;
    }

    float cst = 0.0f;
    for (int tb = 0; tb < 8; ++tb) {
#pragma unroll
        for (int u = 0; u < 14; ++u) {
            const int t = tb * 14 + u;
            // prefetch step t+13 into slot (u+13)%14 (static index); past
            // the end, re-load t=111's row (in-bounds, value unused).
            buf[(u + 13) % 14][0] = P[qp];
            buf[(u + 13) % 14][1] = P[PLANE + qp];
            buf[(u + 13) % 14][2] = P[2 * PLANE + qp];
            buf[(u + 13) % 14][3] = P[3 * PLANE + qp];
            qp += (t < 98) ? dstep : 0;

            float u0 = bf2f(buf[u][0]);
            float u1 = bf2f(buf[u][1]);
            float u2v = bf2f(buf[u][2]);
            float xp = bf2f(buf[u][3]) * SCALE_X;
            float f = sigmoidf_fast(u1 + vf * cst + bfv);
            cst = f * cst + (1.0f - f) * u0;
            float r = sigmoidf_fast(u2v + vr * cst + brv);
            out[oOff] = r * cst + (1.0f - r) * xp;
            oOff += ostep;
        }
    }
}

// ---------------------------------------------------------------------------
// Launch (3 kernels; permute_w2 folded into scan1). Workspace layout (bytes):
//   H1a bf16 [b][p][ch] 8*12544*256       @ 0          (51,380,224)
//   U2t bf16 4 planes [k][b][ch][p]       @ 51380224   (205,520,896)
//   W2t bf16 768*256                      @ 256901120  (393,216)
// ---------------------------------------------------------------------------
extern "C" void kernel_launch(void* const* d_in, const int* in_sizes, int n_in,
                              void* d_out, int out_size, void* d_ws, size_t ws_size,
                              hipStream_t stream) {
    const float* x   = (const float*)d_in[0];
    const float* W1  = (const float*)d_in[1];
    const float* wc1 = (const float*)d_in[2];
    const float* b1  = (const float*)d_in[3];
    const float* W2  = (const float*)d_in[4];
    const float* wc2 = (const float*)d_in[5];
    const float* b2  = (const float*)d_in[6];
    float* out = (float*)d_out;

    char* ws = (char*)d_ws;
    ushort_t* H1a = (ushort_t*)(ws);
    ushort_t* U2t = (ushort_t*)(ws + 51380224);
    ushort_t* W2t = (ushort_t*)(ws + 51380224 + 205520896);

    scan1<<<896, 256, 0, stream>>>(x, W1, wc1, b1, W2, W2t, H1a);
    gemm2<<<4704, 256, 0, stream>>>(H1a, W2t, U2t);
    scan2<<<dim3(128, 8), 256, 0, stream>>>(U2t, wc2, b2, out);
}